// Round 11
// baseline (240.519 us; speedup 1.0000x reference)
//
#include <hip/hip_runtime.h>
#include <hip/hip_bf16.h>

// Attention block: QKV GEMM -> 16-head softmax attention -> proj GEMM.
// B=4, T=2048, C=1024, nh=16, hs=64. All GEMMs in bf16 MFMA, fp32 accum.
// Reference "bug": attn out (B,nh,T,hs) flat is reinterpreted as (B*T, C) for the
// projection -> we just feed the flat [bh][t][d] buffer as proj GEMM's A matrix.
//
// GEMM (r11): 128x128 tile, BK=32, FOUR LDS slots with stage-lead 2 and counted
// s_waitcnt vmcnt(4) before each barrier (T4) -> no vmcnt(0) drain in the steady
// state. Wait-before-barrier makes cross-wave staging visibility sound.
// attn (r10, unchanged): swapped QK^T, no-max exp2 softmax, T12 repack,
// ones-MFMA row-sum, LDS-staged K/V dbuf, XCD remap.

typedef __attribute__((ext_vector_type(8)))  short bf16x8;   // MFMA A/B frag
typedef __attribute__((ext_vector_type(4)))  float f32x4;    // 16x16 C/D frag
typedef __attribute__((ext_vector_type(16))) float f32x16;   // 32x32 C/D frag
typedef __attribute__((ext_vector_type(2)))  unsigned u32x2;

typedef __attribute__((address_space(3))) unsigned lds_u32_t;
typedef __attribute__((address_space(1))) unsigned glb_u32_t;

__device__ __forceinline__ void async_cp16(const short* g, short* l) {
    __builtin_amdgcn_global_load_lds((glb_u32_t*)g, (lds_u32_t*)l, 16, 0, 0);
}

__device__ __forceinline__ float exp2fast(float x) {
    return __builtin_amdgcn_exp2f(x);    // v_exp_f32: 2^x
}

__device__ __forceinline__ short f2bf(float f) {
    union { float f; unsigned u; } v; v.f = f;
    unsigned r = v.u + 0x7fffu + ((v.u >> 16) & 1u);   // RNE (inputs are finite)
    return (short)(r >> 16);
}

__device__ __forceinline__ unsigned cvt_pk_bf16(float lo, float hi) {
    unsigned r;
    asm("v_cvt_pk_bf16_f32 %0, %1, %2" : "=v"(r) : "v"(lo), "v"(hi));
    return r;   // bits[15:0]=bf16(lo), bits[31:16]=bf16(hi)
}

// ---------------- fused fp32 -> bf16 conversion (one launch for all 3 inputs) ----
__global__ __launch_bounds__(256) void cvt3_kernel(
    const float4* __restrict__ x,  const float4* __restrict__ ww,
    const float4* __restrict__ pw, short4* __restrict__ xb,
    short4* __restrict__ wwb,      short4* __restrict__ pwb) {
    const int b = blockIdx.x;
    const float4* in; short4* out; int i;
    if (b < 8192)       { in = x;  out = xb;  i = b * 256 + threadIdx.x; }
    else if (b < 11264) { in = ww; out = wwb; i = (b - 8192) * 256 + threadIdx.x; }
    else                { in = pw; out = pwb; i = (b - 11264) * 256 + threadIdx.x; }
    float4 v = in[i];
    short4 o;
    o.x = f2bf(v.x); o.y = f2bf(v.y); o.z = f2bf(v.z); o.w = f2bf(v.w);
    out[i] = o;
}

// ---------------- GEMM: C[m][n] = sum_k A[m][k]*W[n][k] + bias[n] ----------------
// 128x128 tile, BK=32, 256 threads = 4 waves (2x2), wave owns 64x64 out.
// 4 LDS slots (64KB): STAGE(t+2) at iter t top; pre-barrier wait is vmcnt(4)
// (only t+2's 4 loads in flight; t+1 landed in EVERY wave before the barrier).
// Swizzle: source col pre-swizzled 8*((chunk&3)^(row&3)); read XOR (row&3)*8.
template<int EPI>
__global__ __launch_bounds__(256) void gemm_bf16(
    const short* __restrict__ A, const short* __restrict__ W,
    const float* __restrict__ bias, float* __restrict__ outF,
    short* __restrict__ kout, short* __restrict__ qout, short* __restrict__ vtout,
    int M, int N, int K)
{
    __shared__ short lA[4][128 * 32];
    __shared__ short lB[4][128 * 32];
    const int tid  = threadIdx.x;
    const int lane = tid & 63;
    const int wave = tid >> 6;
    const int wM = (wave >> 1) * 64;
    const int wN = (wave & 1) * 64;
    const int l15 = lane & 15, l4 = lane >> 4;
    const int rsw = (l15 & 3) << 3;             // read-side XOR (shorts)
    const int rowBase = blockIdx.y * 128;
    const int colBase = blockIdx.x * 128;

    auto STAGE = [&](int t, int slot) {         // 4 vmem instrs per thread
        const int k0 = t * 32;
        #pragma unroll
        for (int i = 0; i < 2; ++i) {
            int idx = i * 256 + tid;                  // 0..511 chunk id
            int r   = idx >> 2;                       // tile row 0..127
            int cp  = ((idx & 3) ^ (r & 3)) * 8;      // pre-swizzled source col
            async_cp16(A + (size_t)(rowBase + r) * K + k0 + cp, &lA[slot][idx * 8]);
            async_cp16(W + (size_t)(colBase + r) * K + k0 + cp, &lB[slot][idx * 8]);
        }
    };

    f32x4 acc[4][4] = {};

    auto COMPUTE = [&](int slot) {
        bf16x8 af[4], bfr[4];
        const int co = l4 * 8;
        #pragma unroll
        for (int mt = 0; mt < 4; ++mt)
            af[mt] = *(const bf16x8*)(&lA[slot][(wM + mt * 16 + l15) * 32 + (co ^ rsw)]);
        #pragma unroll
        for (int nt = 0; nt < 4; ++nt)
            bfr[nt] = *(const bf16x8*)(&lB[slot][(wN + nt * 16 + l15) * 32 + (co ^ rsw)]);
        #pragma unroll
        for (int mt = 0; mt < 4; ++mt)
            #pragma unroll
            for (int nt = 0; nt < 4; ++nt)
                acc[mt][nt] = __builtin_amdgcn_mfma_f32_16x16x32_bf16(
                    af[mt], bfr[nt], acc[mt][nt], 0, 0, 0);
    };

    const int NT = K >> 5;   // 32 for K=1024

    STAGE(0, 0);
    STAGE(1, 1);
    asm volatile("s_waitcnt vmcnt(4)" ::: "memory");   // tile 0 landed
    asm volatile("s_barrier" ::: "memory");

    for (int t = 0; t < NT - 2; ++t) {
        STAGE(t + 2, (t + 2) & 3);
        COMPUTE(t & 3);
        asm volatile("s_waitcnt vmcnt(4)" ::: "memory");   // tile t+1 landed
        asm volatile("s_barrier" ::: "memory");
    }
    COMPUTE((NT - 2) & 3);
    asm volatile("s_waitcnt vmcnt(0)" ::: "memory");       // tile NT-1 landed
    asm volatile("s_barrier" ::: "memory");
    COMPUTE((NT - 1) & 3);

    #pragma unroll
    for (int mt = 0; mt < 4; ++mt) {
        #pragma unroll
        for (int nt = 0; nt < 4; ++nt) {
            const int n  = colBase + wN + nt * 16 + l15;
            const int mb = rowBase + wM + mt * 16 + l4 * 4;
            const float bv = bias[n];
            #pragma unroll
            for (int r = 0; r < 4; ++r) {
                const int m = mb + r;
                float val = acc[mt][nt][r] + bv;
                if (EPI == 0) {
                    int b = m >> 11, t = m & 2047;
                    int j = n >> 10, hd = n & 1023;
                    int h = hd >> 6, d = hd & 63;
                    size_t base = ((size_t)(b * 16 + h) * 2048 + t) * 64 + d;
                    // fold hs^-0.5 * log2(e) into Q so softmax runs in exp2 domain
                    if (j == 0)      kout[base] = f2bf(val);
                    else if (j == 1) qout[base] = f2bf(val * 0.180336879f);
                    else             vtout[((size_t)(b * 16 + h) * 64 + d) * 2048 + t] = f2bf(val);
                } else {
                    outF[(size_t)m * N + n] = val;
                }
            }
        }
    }
}

// ---------------- flash attention, swapped-QK^T 32x32x16, LDS-staged K/V --------
// (unchanged from round 10 — passing at 100.6 µs, MfmaUtil 36.6%)
__global__ __launch_bounds__(256) void attn_kernel(
    const short* __restrict__ Q, const short* __restrict__ Km,
    const short* __restrict__ Vt, short* __restrict__ O)
{
    __shared__ short kbuf[2][64 * 64];
    __shared__ short vbuf[2][64 * 64];

    const int tid  = threadIdx.x;
    const int lane = tid & 63;
    const int wave = tid >> 6;
    const int l31 = lane & 31;
    const int l1  = lane >> 5;

    // XCD remap: wg%8 picks the XCD -> give all 16 q-blocks of a head one XCD.
    const int b     = blockIdx.x;
    const int xcd   = b & 7;
    const int inner = b >> 3;
    const int bx    = inner & 15;
    const int bh    = xcd * 8 + (inner >> 4);
    const int q0    = bx * 128 + wave * 32;

    const short* Qh = Q  + (size_t)bh * 2048 * 64;
    const short* Kh = Km + (size_t)bh * 2048 * 64;
    const short* Vh = Vt + (size_t)bh * 64 * 2048;

    const int i8 = lane >> 3, i7 = lane & 7;
    const int srcCol = 8 * (i7 ^ i8);          // pre-swizzled source column (elems)
    const int rsw    = (l31 & 7) << 3;         // read-side swizzle (shorts)

    // Staging: waves 0-1 stage K, waves 2-3 stage V; strength-reduced pointers.
    const short* src[4];
    short* dst0[4];
    int step;
    if (wave < 2) {
        #pragma unroll
        for (int c = 0; c < 4; ++c) {
            int j = wave * 4 + c;
            src[c]  = Kh + (size_t)(8 * j + i8) * 64 + srcCol;
            dst0[c] = &kbuf[0][j * 512 + lane * 8];
        }
        step = 64 * 64;
    } else {
        #pragma unroll
        for (int c = 0; c < 4; ++c) {
            int j = (wave - 2) * 4 + c;
            src[c]  = Vh + (size_t)(8 * j + i8) * 2048 + srcCol;
            dst0[c] = &vbuf[0][j * 512 + lane * 8];
        }
        step = 64;
    }
    auto STAGE = [&](int buf) {
        #pragma unroll
        for (int c = 0; c < 4; ++c) {
            async_cp16(src[c], dst0[c] + buf * 4096);
            src[c] += step;
        }
    };

    // Q as B-operand: n = q = l31, k = d = s*16 + l1*8 + j
    bf16x8 qf[4];
    #pragma unroll
    for (int s = 0; s < 4; ++s)
        qf[s] = *(const bf16x8*)(Qh + (size_t)(q0 + l31) * 64 + s * 16 + l1 * 8);

    // ones B-frag for the row-sum MFMA
    union { unsigned u[4]; bf16x8 v; } onesu;
    #pragma unroll
    for (int j = 0; j < 4; ++j) onesu.u[j] = 0x3F803F80u;
    const bf16x8 onesf = onesu.v;

    f32x16 o[2] = {};
    f32x16 ol   = {};     // row-sums, same reg mapping as o

    STAGE(0);
    __syncthreads();

    int cur = 0;
    for (int it = 0; it < 32; ++it) {
        if (it < 31) STAGE(cur ^ 1);   // prefetch next tile (in flight all phase)

        // ---- QK^T swapped: s2[t] = K_tile(t) x Q  -> D[kv][q], q = l31
        f32x16 s2[2] = {};
        __builtin_amdgcn_s_setprio(1);
        #pragma unroll
        for (int t = 0; t < 2; ++t) {
            #pragma unroll
            for (int s = 0; s < 4; ++s) {
                bf16x8 kf = *(const bf16x8*)(
                    &kbuf[cur][(t * 32 + l31) * 64 + ((s * 16 + l1 * 8) ^ rsw)]);
                s2[t] = __builtin_amdgcn_mfma_f32_32x32x16_bf16(kf, qf[s], s2[t], 0, 0, 0);
            }
        }
        __builtin_amdgcn_s_setprio(0);

        // ---- P = exp2(s) (no max subtraction)
        #pragma unroll
        for (int t = 0; t < 2; ++t)
            #pragma unroll
            for (int i = 0; i < 16; ++i)
                s2[t][i] = exp2fast(s2[t][i]);

        // ---- pack P into A-frags: cvt_pk pairs + permlane32_swap (verified r6)
        bf16x8 pa[4];
        #pragma unroll
        for (int t = 0; t < 2; ++t) {
            #pragma unroll
            for (int sl = 0; sl < 2; ++sl) {
                unsigned A0 = cvt_pk_bf16(s2[t][8 * sl + 0], s2[t][8 * sl + 1]);
                unsigned A1 = cvt_pk_bf16(s2[t][8 * sl + 2], s2[t][8 * sl + 3]);
                unsigned B0 = cvt_pk_bf16(s2[t][8 * sl + 4], s2[t][8 * sl + 5]);
                unsigned B1 = cvt_pk_bf16(s2[t][8 * sl + 6], s2[t][8 * sl + 7]);
                u32x2 ra = __builtin_amdgcn_permlane32_swap(A0, B0, false, false);
                u32x2 rb = __builtin_amdgcn_permlane32_swap(A1, B1, false, false);
                union { unsigned u[4]; bf16x8 v; } w;
                w.u[0] = ra.x;
                w.u[1] = rb.x;
                w.u[2] = ra.y;
                w.u[3] = rb.y;
                pa[2 * t + sl] = w.v;
            }
        }

        // ---- PV + row-sum: o[dt] += P x V, ol += P x 1  (V frags from LDS)
        __builtin_amdgcn_s_setprio(1);
        #pragma unroll
        for (int s = 0; s < 4; ++s) {
            #pragma unroll
            for (int dt = 0; dt < 2; ++dt) {
                bf16x8 vf = *(const bf16x8*)(
                    &vbuf[cur][(dt * 32 + l31) * 64 + ((s * 16 + l1 * 8) ^ rsw)]);
                o[dt] = __builtin_amdgcn_mfma_f32_32x32x16_bf16(pa[s], vf, o[dt], 0, 0, 0);
            }
            ol = __builtin_amdgcn_mfma_f32_32x32x16_bf16(pa[s], onesf, ol, 0, 0, 0);
        }
        __builtin_amdgcn_s_setprio(0);

        __syncthreads();   // drains prefetch (vmcnt 0) + read-done before overwrite
        cur ^= 1;
    }

    // ---- epilogue: normalize by lane-local 1/ol[r] (same reg mapping as o)
    #pragma unroll
    for (int g = 0; g < 4; ++g)
        #pragma unroll
        for (int rr = 0; rr < 4; ++rr) {
            float invl = 1.f / ol[g * 4 + rr];
            int qrow = q0 + rr + 8 * g + 4 * l1;
            size_t base = ((size_t)bh * 2048 + qrow) * 64 + l31;
            O[base]      = f2bf(o[0][g * 4 + rr] * invl);
            O[base + 32] = f2bf(o[1][g * 4 + rr] * invl);
        }
}

// ---------------- launcher ----------------
extern "C" void kernel_launch(void* const* d_in, const int* in_sizes, int n_in,
                              void* d_out, int out_size, void* d_ws, size_t ws_size,
                              hipStream_t stream) {
    const float* x  = (const float*)d_in[0];   // (4,2048,1024)
    const float* ww = (const float*)d_in[1];   // (3072,1024)
    const float* wb = (const float*)d_in[2];   // (3072,)
    const float* pwt = (const float*)d_in[3];  // (1024,1024)
    const float* pb  = (const float*)d_in[4];  // (1024,)
    float* out = (float*)d_out;                // (4,2048,1024) fp32

    short* ws  = (short*)d_ws;
    short* xb  = ws;                      // 8192*1024
    short* wwb = xb  + 8192 * 1024;       // 3072*1024
    short* pwb = wwb + 3072 * 1024;       // 1024*1024
    short* qb  = pwb + 1024 * 1024;       // 64*2048*64  [bh][t][d] (pre-scaled)
    short* kb  = qb  + 64 * 2048 * 64;    // 64*2048*64  [bh][t][d]
    short* vtb = kb  + 64 * 2048 * 64;    // 64*64*2048  [bh][d][t]
    short* ob  = vtb + 64 * 2048 * 64;    // 64*2048*64  flat = proj A matrix

    cvt3_kernel<<<12288, 256, 0, stream>>>(
        (const float4*)x, (const float4*)ww, (const float4*)pwt,
        (short4*)xb, (short4*)wwb, (short4*)pwb);

    gemm_bf16<0><<<dim3(24, 64), 256, 0, stream>>>(
        xb, wwb, wb, nullptr, kb, qb, vtb, 8192, 3072, 1024);

    attn_kernel<<<1024, 256, 0, stream>>>(qb, kb, vtb, ob);

    gemm_bf16<1><<<dim3(8, 64), 256, 0, stream>>>(
        ob, pwb, pb, out, nullptr, nullptr, nullptr, 8192, 1024, 1024);
}

// Round 12
// 215.474 us; speedup vs baseline: 1.1162x; 1.1162x over previous
//
#include <hip/hip_runtime.h>
#include <hip/hip_bf16.h>

// Attention block: QKV GEMM -> 16-head softmax attention -> proj GEMM.
// B=4, T=2048, C=1024, nh=16, hs=64. All GEMMs in bf16 MFMA, fp32 accum.
// Reference "bug": attn out (B,nh,T,hs) flat is reinterpreted as (B*T, C) for the
// projection -> we just feed the flat [bh][t][d] buffer as proj GEMM's A matrix.
//
// GEMM (r9 structure, reverted from failed r11 BK=32 experiment): 128x128 tile,
// BK=64, 2-slot double-buffered global_load_lds prefetch (issue next tile before
// computing current), pre-swizzled source + XOR read. ~700 TF = 2-phase ceiling.
// attn (r10, unchanged): swapped QK^T, no-max exp2 softmax, T12 repack,
// ones-MFMA row-sum, LDS-staged K/V dbuf, XCD remap.

typedef __attribute__((ext_vector_type(8)))  short bf16x8;   // MFMA A/B frag
typedef __attribute__((ext_vector_type(4)))  float f32x4;    // 16x16 C/D frag
typedef __attribute__((ext_vector_type(16))) float f32x16;   // 32x32 C/D frag
typedef __attribute__((ext_vector_type(2)))  unsigned u32x2;

typedef __attribute__((address_space(3))) unsigned lds_u32_t;
typedef __attribute__((address_space(1))) unsigned glb_u32_t;

__device__ __forceinline__ void async_cp16(const short* g, short* l) {
    __builtin_amdgcn_global_load_lds((glb_u32_t*)g, (lds_u32_t*)l, 16, 0, 0);
}

__device__ __forceinline__ float exp2fast(float x) {
    return __builtin_amdgcn_exp2f(x);    // v_exp_f32: 2^x
}

__device__ __forceinline__ short f2bf(float f) {
    union { float f; unsigned u; } v; v.f = f;
    unsigned r = v.u + 0x7fffu + ((v.u >> 16) & 1u);   // RNE (inputs are finite)
    return (short)(r >> 16);
}

__device__ __forceinline__ unsigned cvt_pk_bf16(float lo, float hi) {
    unsigned r;
    asm("v_cvt_pk_bf16_f32 %0, %1, %2" : "=v"(r) : "v"(lo), "v"(hi));
    return r;   // bits[15:0]=bf16(lo), bits[31:16]=bf16(hi)
}

// ---------------- fused fp32 -> bf16 conversion (one launch for all 3 inputs) ----
__global__ __launch_bounds__(256) void cvt3_kernel(
    const float4* __restrict__ x,  const float4* __restrict__ ww,
    const float4* __restrict__ pw, short4* __restrict__ xb,
    short4* __restrict__ wwb,      short4* __restrict__ pwb) {
    const int b = blockIdx.x;
    const float4* in; short4* out; int i;
    if (b < 8192)       { in = x;  out = xb;  i = b * 256 + threadIdx.x; }
    else if (b < 11264) { in = ww; out = wwb; i = (b - 8192) * 256 + threadIdx.x; }
    else                { in = pw; out = pwb; i = (b - 11264) * 256 + threadIdx.x; }
    float4 v = in[i];
    short4 o;
    o.x = f2bf(v.x); o.y = f2bf(v.y); o.z = f2bf(v.z); o.w = f2bf(v.w);
    out[i] = o;
}

// ---------------- GEMM: C[m][n] = sum_k A[m][k]*W[n][k] + bias[n] ----------------
// 128x128 tile, BK=64, 256 threads = 4 waves (2x2), wave owns 64x64 out.
// Double-buffered LDS (64KB): STAGE(t+1) issued BEFORE compute(t); single
// __syncthreads per K-step drains the (now-covered) prefetch.
// LDS layout: linear dest (global_load_lds), source col pre-swizzled by
// 8*((idx&7)^(row&7)); reads XOR col with (row&7)*8 -> stage-then-read = id.
template<int EPI>
__global__ __launch_bounds__(256) void gemm_bf16(
    const short* __restrict__ A, const short* __restrict__ W,
    const float* __restrict__ bias, float* __restrict__ outF,
    short* __restrict__ kout, short* __restrict__ qout, short* __restrict__ vtout,
    int M, int N, int K)
{
    __shared__ short lA[2][128 * 64];
    __shared__ short lB[2][128 * 64];
    const int tid  = threadIdx.x;
    const int lane = tid & 63;
    const int wave = tid >> 6;
    const int wM = (wave >> 1) * 64;
    const int wN = (wave & 1) * 64;
    const int l15 = lane & 15, l4 = lane >> 4;
    const int rsw = (lane & 7) << 3;            // read-side XOR (shorts)
    const int rowBase = blockIdx.y * 128;
    const int colBase = blockIdx.x * 128;

    auto STAGE = [&](int t, int buf) {
        const int k0 = t * 64;
        #pragma unroll
        for (int i = 0; i < 4; ++i) {
            int idx = i * 256 + tid;
            int r   = idx >> 3;                       // tile row 0..127
            int cp  = ((idx & 7) ^ (r & 7)) * 8;      // pre-swizzled source col
            int eo  = idx * 8;                        // linear LDS offset (shorts)
            async_cp16(A + (size_t)(rowBase + r) * K + k0 + cp, &lA[buf][eo]);
            async_cp16(W + (size_t)(colBase + r) * K + k0 + cp, &lB[buf][eo]);
        }
    };

    f32x4 acc[4][4] = {};
    const int NT = K >> 6;

    STAGE(0, 0);
    __syncthreads();

    int cur = 0;
    for (int t = 0; t < NT; ++t) {
        if (t + 1 < NT) STAGE(t + 1, cur ^ 1);   // prefetch: in flight all phase
        #pragma unroll
        for (int kt = 0; kt < 2; ++kt) {
            bf16x8 af[4], bfr[4];
            #pragma unroll
            for (int mt = 0; mt < 4; ++mt)
                af[mt] = *(const bf16x8*)(
                    &lA[cur][(wM + mt * 16 + l15) * 64 + ((kt * 32 + l4 * 8) ^ rsw)]);
            #pragma unroll
            for (int nt = 0; nt < 4; ++nt)
                bfr[nt] = *(const bf16x8*)(
                    &lB[cur][(wN + nt * 16 + l15) * 64 + ((kt * 32 + l4 * 8) ^ rsw)]);
            #pragma unroll
            for (int mt = 0; mt < 4; ++mt)
                #pragma unroll
                for (int nt = 0; nt < 4; ++nt)
                    acc[mt][nt] = __builtin_amdgcn_mfma_f32_16x16x32_bf16(
                        af[mt], bfr[nt], acc[mt][nt], 0, 0, 0);
        }
        __syncthreads();   // drains prefetch vmcnt + read-done before overwrite
        cur ^= 1;
    }

    #pragma unroll
    for (int mt = 0; mt < 4; ++mt) {
        #pragma unroll
        for (int nt = 0; nt < 4; ++nt) {
            const int n  = colBase + wN + nt * 16 + l15;
            const int mb = rowBase + wM + mt * 16 + l4 * 4;
            const float bv = bias[n];
            #pragma unroll
            for (int r = 0; r < 4; ++r) {
                const int m = mb + r;
                float val = acc[mt][nt][r] + bv;
                if (EPI == 0) {
                    int b = m >> 11, t = m & 2047;
                    int j = n >> 10, hd = n & 1023;
                    int h = hd >> 6, d = hd & 63;
                    size_t base = ((size_t)(b * 16 + h) * 2048 + t) * 64 + d;
                    // fold hs^-0.5 * log2(e) into Q so softmax runs in exp2 domain
                    if (j == 0)      kout[base] = f2bf(val);
                    else if (j == 1) qout[base] = f2bf(val * 0.180336879f);
                    else             vtout[((size_t)(b * 16 + h) * 64 + d) * 2048 + t] = f2bf(val);
                } else {
                    outF[(size_t)m * N + n] = val;
                }
            }
        }
    }
}

// ---------------- flash attention, swapped-QK^T 32x32x16, LDS-staged K/V --------
// (unchanged from round 10 — passing at 100.6 µs, MfmaUtil 36.6%)
__global__ __launch_bounds__(256) void attn_kernel(
    const short* __restrict__ Q, const short* __restrict__ Km,
    const short* __restrict__ Vt, short* __restrict__ O)
{
    __shared__ short kbuf[2][64 * 64];
    __shared__ short vbuf[2][64 * 64];

    const int tid  = threadIdx.x;
    const int lane = tid & 63;
    const int wave = tid >> 6;
    const int l31 = lane & 31;
    const int l1  = lane >> 5;

    // XCD remap: wg%8 picks the XCD -> give all 16 q-blocks of a head one XCD.
    const int b     = blockIdx.x;
    const int xcd   = b & 7;
    const int inner = b >> 3;
    const int bx    = inner & 15;
    const int bh    = xcd * 8 + (inner >> 4);
    const int q0    = bx * 128 + wave * 32;

    const short* Qh = Q  + (size_t)bh * 2048 * 64;
    const short* Kh = Km + (size_t)bh * 2048 * 64;
    const short* Vh = Vt + (size_t)bh * 64 * 2048;

    const int i8 = lane >> 3, i7 = lane & 7;
    const int srcCol = 8 * (i7 ^ i8);          // pre-swizzled source column (elems)
    const int rsw    = (l31 & 7) << 3;         // read-side swizzle (shorts)

    // Staging: waves 0-1 stage K, waves 2-3 stage V; strength-reduced pointers.
    const short* src[4];
    short* dst0[4];
    int step;
    if (wave < 2) {
        #pragma unroll
        for (int c = 0; c < 4; ++c) {
            int j = wave * 4 + c;
            src[c]  = Kh + (size_t)(8 * j + i8) * 64 + srcCol;
            dst0[c] = &kbuf[0][j * 512 + lane * 8];
        }
        step = 64 * 64;
    } else {
        #pragma unroll
        for (int c = 0; c < 4; ++c) {
            int j = (wave - 2) * 4 + c;
            src[c]  = Vh + (size_t)(8 * j + i8) * 2048 + srcCol;
            dst0[c] = &vbuf[0][j * 512 + lane * 8];
        }
        step = 64;
    }
    auto STAGE = [&](int buf) {
        #pragma unroll
        for (int c = 0; c < 4; ++c) {
            async_cp16(src[c], dst0[c] + buf * 4096);
            src[c] += step;
        }
    };

    // Q as B-operand: n = q = l31, k = d = s*16 + l1*8 + j
    bf16x8 qf[4];
    #pragma unroll
    for (int s = 0; s < 4; ++s)
        qf[s] = *(const bf16x8*)(Qh + (size_t)(q0 + l31) * 64 + s * 16 + l1 * 8);

    // ones B-frag for the row-sum MFMA
    union { unsigned u[4]; bf16x8 v; } onesu;
    #pragma unroll
    for (int j = 0; j < 4; ++j) onesu.u[j] = 0x3F803F80u;
    const bf16x8 onesf = onesu.v;

    f32x16 o[2] = {};
    f32x16 ol   = {};     // row-sums, same reg mapping as o

    STAGE(0);
    __syncthreads();

    int cur = 0;
    for (int it = 0; it < 32; ++it) {
        if (it < 31) STAGE(cur ^ 1);   // prefetch next tile (in flight all phase)

        // ---- QK^T swapped: s2[t] = K_tile(t) x Q  -> D[kv][q], q = l31
        f32x16 s2[2] = {};
        __builtin_amdgcn_s_setprio(1);
        #pragma unroll
        for (int t = 0; t < 2; ++t) {
            #pragma unroll
            for (int s = 0; s < 4; ++s) {
                bf16x8 kf = *(const bf16x8*)(
                    &kbuf[cur][(t * 32 + l31) * 64 + ((s * 16 + l1 * 8) ^ rsw)]);
                s2[t] = __builtin_amdgcn_mfma_f32_32x32x16_bf16(kf, qf[s], s2[t], 0, 0, 0);
            }
        }
        __builtin_amdgcn_s_setprio(0);

        // ---- P = exp2(s) (no max subtraction)
        #pragma unroll
        for (int t = 0; t < 2; ++t)
            #pragma unroll
            for (int i = 0; i < 16; ++i)
                s2[t][i] = exp2fast(s2[t][i]);

        // ---- pack P into A-frags: cvt_pk pairs + permlane32_swap (verified r6)
        bf16x8 pa[4];
        #pragma unroll
        for (int t = 0; t < 2; ++t) {
            #pragma unroll
            for (int sl = 0; sl < 2; ++sl) {
                unsigned A0 = cvt_pk_bf16(s2[t][8 * sl + 0], s2[t][8 * sl + 1]);
                unsigned A1 = cvt_pk_bf16(s2[t][8 * sl + 2], s2[t][8 * sl + 3]);
                unsigned B0 = cvt_pk_bf16(s2[t][8 * sl + 4], s2[t][8 * sl + 5]);
                unsigned B1 = cvt_pk_bf16(s2[t][8 * sl + 6], s2[t][8 * sl + 7]);
                u32x2 ra = __builtin_amdgcn_permlane32_swap(A0, B0, false, false);
                u32x2 rb = __builtin_amdgcn_permlane32_swap(A1, B1, false, false);
                union { unsigned u[4]; bf16x8 v; } w;
                w.u[0] = ra.x;
                w.u[1] = rb.x;
                w.u[2] = ra.y;
                w.u[3] = rb.y;
                pa[2 * t + sl] = w.v;
            }
        }

        // ---- PV + row-sum: o[dt] += P x V, ol += P x 1  (V frags from LDS)
        __builtin_amdgcn_s_setprio(1);
        #pragma unroll
        for (int s = 0; s < 4; ++s) {
            #pragma unroll
            for (int dt = 0; dt < 2; ++dt) {
                bf16x8 vf = *(const bf16x8*)(
                    &vbuf[cur][(dt * 32 + l31) * 64 + ((s * 16 + l1 * 8) ^ rsw)]);
                o[dt] = __builtin_amdgcn_mfma_f32_32x32x16_bf16(pa[s], vf, o[dt], 0, 0, 0);
            }
            ol = __builtin_amdgcn_mfma_f32_32x32x16_bf16(pa[s], onesf, ol, 0, 0, 0);
        }
        __builtin_amdgcn_s_setprio(0);

        __syncthreads();   // drains prefetch (vmcnt 0) + read-done before overwrite
        cur ^= 1;
    }

    // ---- epilogue: normalize by lane-local 1/ol[r] (same reg mapping as o)
    #pragma unroll
    for (int g = 0; g < 4; ++g)
        #pragma unroll
        for (int rr = 0; rr < 4; ++rr) {
            float invl = 1.f / ol[g * 4 + rr];
            int qrow = q0 + rr + 8 * g + 4 * l1;
            size_t base = ((size_t)bh * 2048 + qrow) * 64 + l31;
            O[base]      = f2bf(o[0][g * 4 + rr] * invl);
            O[base + 32] = f2bf(o[1][g * 4 + rr] * invl);
        }
}

// ---------------- launcher ----------------
extern "C" void kernel_launch(void* const* d_in, const int* in_sizes, int n_in,
                              void* d_out, int out_size, void* d_ws, size_t ws_size,
                              hipStream_t stream) {
    const float* x  = (const float*)d_in[0];   // (4,2048,1024)
    const float* ww = (const float*)d_in[1];   // (3072,1024)
    const float* wb = (const float*)d_in[2];   // (3072,)
    const float* pwt = (const float*)d_in[3];  // (1024,1024)
    const float* pb  = (const float*)d_in[4];  // (1024,)
    float* out = (float*)d_out;                // (4,2048,1024) fp32

    short* ws  = (short*)d_ws;
    short* xb  = ws;                      // 8192*1024
    short* wwb = xb  + 8192 * 1024;       // 3072*1024
    short* pwb = wwb + 3072 * 1024;       // 1024*1024
    short* qb  = pwb + 1024 * 1024;       // 64*2048*64  [bh][t][d] (pre-scaled)
    short* kb  = qb  + 64 * 2048 * 64;    // 64*2048*64  [bh][t][d]
    short* vtb = kb  + 64 * 2048 * 64;    // 64*64*2048  [bh][d][t]
    short* ob  = vtb + 64 * 2048 * 64;    // 64*2048*64  flat = proj A matrix

    cvt3_kernel<<<12288, 256, 0, stream>>>(
        (const float4*)x, (const float4*)ww, (const float4*)pwt,
        (short4*)xb, (short4*)wwb, (short4*)pwb);

    gemm_bf16<0><<<dim3(24, 64), 256, 0, stream>>>(
        xb, wwb, wb, nullptr, kb, qb, vtb, 8192, 3072, 1024);

    attn_kernel<<<1024, 256, 0, stream>>>(qb, kb, vtb, ob);

    gemm_bf16<1><<<dim3(8, 64), 256, 0, stream>>>(
        ob, pwb, pb, out, nullptr, nullptr, nullptr, 8192, 1024, 1024);
}